// Round 4
// baseline (842.219 us; speedup 1.0000x reference)
//
#include <hip/hip_runtime.h>

// Attractor: hs <- normalize(leaky_relu(0.5*hs + h@M)), TAU=16, B=8, D=8192 (fp32 I/O).
//
// R7 = R6 resubmit + rule-#18 hardening (sched_barrier(0) after each manual
// s_waitcnt). R6's bench failed at container level (no compile/correctness
// error); address/hang audit found no kernel-side fault mechanism.
//
// R6 design: R5 post-mortem showed 816 us; steps ~45 us = 3.0 TB/s on the
// L3-resident 128 MiB Bpack stream = ~4.9 B/cyc/CU = ~4 KiB in flight per CU at
// ~800 cyc L3 latency. Register-destination batching is VGPR-capped (16 b128
// loads = 64 VGPR = half the budget at 16 waves/CU) -> in-flight bytes can't
// grow. R6 streams B via global_load_lds (destinations in LDS, not VGPRs):
//   - per wave: 4-deep rolling pipeline of (A->reg, B->LDS slot) pairs,
//     counted s_waitcnt vmcnt(6) per iter (never 0 in steady state), refill
//     pair i+4 after MFMA i. Tail drains 6->4->2->0. Full unroll = static slots.
//   - LDS: 8 waves x 4 slots x 1 KiB = 32 KiB + 8.5 KiB reduce -> 2 blocks/CU,
//     16 waves/CU; in-flight ceiling ~100 KiB/CU vs ~15 KiB needed for >10 B/cyc.
// Everything else unchanged from R5: 512 blocks x 8 waves, block = 1 n-tile
// (16 cols) x full K; Bpack [nt][kt][lane][8] bf16; A hi/lo trick (rows 0-7 =
// bf16(h), 8-15 = bf16(h-hi), epilogue sums D[r]+D[r+8]); D mapping col=lane&15,
// row=(lane>>4)*4+reg (m89); ss atomics spread over 8 slots/row.

#define DD 8192
#define BB 8
#define TAU 16
#define NT 512      // n-tiles (16 cols each)
#define KT 256      // k-tiles (32 k each)
#define DECAYF 0.5f
#define SLOPEF 0.01f
#define EPSF 1e-12f

typedef __attribute__((ext_vector_type(8))) short short8v;
typedef __attribute__((ext_vector_type(8))) unsigned short ushort8v;
typedef __attribute__((ext_vector_type(4))) float float4v;

#define GLOAD_LDS16(gp, lp)                                                          \
    __builtin_amdgcn_global_load_lds((const __attribute__((address_space(1))) void*)(gp), \
                                     (__attribute__((address_space(3))) void*)(lp), 16, 0, 0)

static __device__ __forceinline__ float b2f(unsigned short u) {
    union { unsigned int i; float f; } v; v.i = ((unsigned int)u) << 16; return v.f;
}
static __device__ __forceinline__ unsigned short f2b(float f) {
    union { float f; unsigned int i; } v; v.f = f;
    unsigned int r = v.i + 0x7FFFu + ((v.i >> 16) & 1u);   // RNE
    return (unsigned short)(r >> 16);
}

// M fp32 (k-major rows, n contiguous) -> Bpack bf16 fragments.
// Fragment slot (lane l, elem j) of tile (nt,kt) = M[kt*32 + 8*(l>>4) + j][nt*16 + (l&15)].
__global__ __launch_bounds__(256) void pack_M_kernel(const float* __restrict__ M,
                                                     unsigned short* __restrict__ Bp) {
    const int w = threadIdx.x >> 6, l = threadIdx.x & 63;
    const unsigned int wid = blockIdx.x * 4 + w;   // 0..131071
    const int kt = wid >> 9;                       // 0..255
    const int nt = wid & 511;                      // 0..511
    const int col = nt * 16 + (l & 15);
    const int k0  = kt * 32 + (l >> 4) * 8;
    const float* src = M + (size_t)k0 * DD + col;
    ushort8v o;
#pragma unroll
    for (int j = 0; j < 8; j++) o[j] = f2b(__builtin_nontemporal_load(src + (size_t)j * DD));
    *(ushort8v*)(Bp + ((size_t)nt * KT + kt) * 512 + (size_t)l * 8) = o;
}

// x fp32 (8 x 8192) -> A fragments for step 0. Rows 0-7 hi, 8-15 lo.
__global__ __launch_bounds__(256) void pack_x_kernel(const float* __restrict__ x,
                                                     unsigned short* __restrict__ Ap) {
    const int w = threadIdx.x >> 6, l = threadIdx.x & 63;
    const int kt = blockIdx.x * 4 + w;             // 0..255
    const int row = l & 15;
    const int k0  = kt * 32 + (l >> 4) * 8;
    const float* src = x + (size_t)(row & 7) * DD + k0;
    ushort8v o;
#pragma unroll
    for (int j = 0; j < 8; j++) {
        const float v = src[j];
        const unsigned short h = f2b(v);
        o[j] = (row < 8) ? h : f2b(v - b2f(h));
    }
    *(ushort8v*)(Ap + (size_t)kt * 512 + (size_t)l * 8) = o;
}

// One full recurrence step. 512 blocks x 512 threads (8 waves), 2 blocks/CU.
// Block owns n-tile bid (16 cols), full K. Wave w: k-tiles [w*32, w*32+32).
__global__ __launch_bounds__(512, 4) void step_kernel(const unsigned short* __restrict__ Ap_cur,
                                                      const unsigned short* __restrict__ Bp,
                                                      const float* __restrict__ act_prev,
                                                      const float* __restrict__ ss_prev,
                                                      float* __restrict__ act_new,
                                                      unsigned short* __restrict__ Ap_next,
                                                      float* __restrict__ ss_new) {
    const int tid = threadIdx.x;
    const int w = tid >> 6, l = tid & 63;
    const int bid = blockIdx.x;
    const int col0 = bid * 16;

    __shared__ unsigned int shB[8][4][256];   // per-wave 4-slot B staging (1 KiB/slot)
    __shared__ float red[8][16][17];

    float4v acc = {0.f, 0.f, 0.f, 0.f};
    const unsigned short* Ab = Ap_cur + (size_t)(w * 32) * 512 + (size_t)l * 8;
    const unsigned short* Bb = Bp + ((size_t)bid * KT + w * 32) * 512 + (size_t)l * 8;

    short8v av[4];
    // Prologue: pairs (A->reg, B->LDS) for tiles 0..3. Pair order makes tile i's
    // two ops the oldest two at iteration i -> vmcnt(6) guarantees both landed.
#pragma unroll
    for (int t = 0; t < 4; t++) {
        av[t] = *(const short8v*)(Ab + (size_t)t * 512);
        GLOAD_LDS16(Bb + (size_t)t * 512, &shB[w][t][0]);
    }

#pragma unroll
    for (int i = 0; i < 32; i++) {
        // Counted wait: steady state keeps 3 pairs (6 ops) in flight across it.
        if (i <= 28)      asm volatile("s_waitcnt vmcnt(6)" ::: "memory");
        else if (i == 29) asm volatile("s_waitcnt vmcnt(4)" ::: "memory");
        else if (i == 30) asm volatile("s_waitcnt vmcnt(2)" ::: "memory");
        else              asm volatile("s_waitcnt vmcnt(0)" ::: "memory");
        __builtin_amdgcn_sched_barrier(0);   // rule #18: pin schedule at the wait

        const short8v b = *(const short8v*)((const unsigned short*)&shB[w][i & 3][0] + (size_t)l * 8);
        acc = __builtin_amdgcn_mfma_f32_16x16x32_bf16(av[i & 3], b, acc, 0, 0, 0);

        if (i + 4 < 32) {   // refill pair i+4 into the slot just consumed
            av[i & 3] = *(const short8v*)(Ab + (size_t)(i + 4) * 512);
            GLOAD_LDS16(Bb + (size_t)(i + 4) * 512, &shB[w][i & 3][0]);
        }
    }

    // De-fragment + cross-wave K reduction in LDS.
    // D layout: col = lane&15, row = (lane>>4)*4 + reg (m89).
    {
        const int rbase = (l >> 4) * 4, c = l & 15;
#pragma unroll
        for (int q = 0; q < 4; q++) red[w][rbase + q][c] = acc[q];
    }
    __syncthreads();

    if (tid < 128) {
        const int r = tid >> 4, c = tid & 15;
        float s = 0.f;
#pragma unroll
        for (int u = 0; u < 8; u++) s += red[u][r][c] + red[u][r + 8][c];  // hi + lo
        float v;
        if (ss_prev) {
            float ss = 0.f;
#pragma unroll
            for (int u = 0; u < 8; u++) ss += ss_prev[r * 8 + u];
            const float inv = 1.0f / fmaxf(sqrtf(ss), EPSF);
            v = inv * (s + DECAYF * act_prev[(size_t)r * DD + col0 + c]);
        } else {
            v = s;   // step 0: hs_prev = 0, h = x
        }
        const float a = (v >= 0.f) ? v : SLOPEF * v;
        act_new[(size_t)r * DD + col0 + c] = a;

        float t2 = a * a;
#pragma unroll
        for (int off = 8; off > 0; off >>= 1) t2 += __shfl_down(t2, off, 16);
        if ((tid & 15) == 0) atomicAdd(&ss_new[r * 8 + (bid & 7)], t2);

        red[0][r][c] = a;   // stage act for the A-pack phase
    }
    __syncthreads();

    // Pack this block's 16 cols = half of A k-tile (bid>>1) for the next step.
    // Lanes with (l>>5) == (bid&1) own k-offsets {0..15} / {16..31} of the tile.
    if (w == 0 && (l >> 5) == (bid & 1)) {
        const int row = l & 15;
        const int kb  = 8 * (l >> 4) - 16 * (bid & 1);   // 0 or 8
        ushort8v o;
#pragma unroll
        for (int j = 0; j < 8; j++) {
            const float v = red[0][row & 7][kb + j];
            const unsigned short h = f2b(v);
            o[j] = (row < 8) ? h : f2b(v - b2f(h));
        }
        *(ushort8v*)(Ap_next + (size_t)(bid >> 1) * 512 + (size_t)l * 8) = o;
    }
}

// out = act * inv(sum of 8 ss slots per row). grid 64 x 1024.
__global__ __launch_bounds__(1024) void scale_kernel(const float* __restrict__ act,
                                                     const float* __restrict__ ss,
                                                     float* __restrict__ out) {
    const int e = blockIdx.x * 1024 + threadIdx.x;
    const int r = e >> 13;
    float s = 0.f;
#pragma unroll
    for (int u = 0; u < 8; u++) s += ss[r * 8 + u];
    const float inv = 1.0f / fmaxf(sqrtf(s), EPSF);
    out[e] = act[e] * inv;
}

extern "C" void kernel_launch(void* const* d_in, const int* in_sizes, int n_in,
                              void* d_out, int out_size, void* d_ws, size_t ws_size,
                              hipStream_t stream) {
    const float* x = (const float*)d_in[0];   // (8, 8192)
    const float* M = (const float*)d_in[1];   // (8192, 8192)

    const size_t szB = (size_t)NT * KT * 1024;               // Bpack: 128 MiB
    const size_t szA = (size_t)KT * 1024;                    // Apack: 256 KiB
    const size_t szF = (size_t)BB * DD * sizeof(float);      // act:   256 KiB
    const size_t szS = (size_t)TAU * BB * 8 * sizeof(float); // ss: 4 KiB (8 slots/row)

    char* p = (char*)d_ws;
    unsigned short* Bp  = (unsigned short*)p; p += szB;
    unsigned short* Ap0 = (unsigned short*)p; p += szA;
    unsigned short* Ap1 = (unsigned short*)p; p += szA;
    float* act0 = (float*)p; p += szF;
    float* act1 = (float*)p; p += szF;
    float* row_ss = (float*)p;

    hipMemsetAsync(row_ss, 0, szS, stream);
    pack_x_kernel<<<64, 256, 0, stream>>>(x, Ap0);
    pack_M_kernel<<<32768, 256, 0, stream>>>(M, Bp);

    unsigned short* Aps[2] = {Ap0, Ap1};
    float* acts[2] = {act0, act1};
    for (int t = 0; t < TAU; t++) {
        step_kernel<<<512, 512, 0, stream>>>(
            Aps[t & 1], Bp,
            acts[(t + 1) & 1],
            t ? (row_ss + (t - 1) * BB * 8) : (const float*)nullptr,
            acts[t & 1],
            Aps[(t + 1) & 1],
            row_ss + t * BB * 8);
    }
    scale_kernel<<<64, 1024, 0, stream>>>(acts[1], row_ss + (TAU - 1) * BB * 8, (float*)d_out);
}